// Round 10
// baseline (717.109 us; speedup 1.0000x reference)
//
#include <hip/hip_runtime.h>
#include <hip/hip_bf16.h>
#include <stdint.h>

// Problem dims (fixed): B=256, T=512, I=512, L=128, D=4, O=2
// GEMM: M = B*T = 131072, N = L*D = 512, K = I = 512
// merged workspace layout: mt[b][l][t]  (t contiguous), b_liq folded in.

typedef __bf16 bf16x8 __attribute__((ext_vector_type(8)));
typedef float f32x4_t __attribute__((ext_vector_type(4)));

__device__ inline unsigned short f2bf(float f) {
    union { float f; unsigned u; } v; v.f = f;
    unsigned r = v.u + 0x7fffu + ((v.u >> 16) & 1u);   // round-to-nearest-even
    return (unsigned short)(r >> 16);
}

// LDS-only barrier: orders DS ops without draining vmcnt (keeps lane-private
// global prefetches in flight across it).
__device__ inline void lds_barrier() {
    asm volatile("s_waitcnt lgkmcnt(0)" ::: "memory");
    __builtin_amdgcn_s_barrier();
}

// VALU butterfly sums over lane-bit 4 / bit 5 (alias-proof, from R9).
__device__ inline float bfly16_add(float x) {
    float a, b;
    asm volatile("v_mov_b32 %0, %2\n\t"
                 "v_mov_b32 %1, %2\n\t"
                 "v_permlane16_swap_b32 %0, %1"
                 : "=&v"(a), "=&v"(b) : "v"(x));
    return a + b;
}
__device__ inline float bfly32_add(float x) {
    float a, b;
    asm volatile("v_mov_b32 %0, %2\n\t"
                 "v_mov_b32 %1, %2\n\t"
                 "v_permlane32_swap_b32 %0, %1"
                 : "=&v"(a), "=&v"(b) : "v"(x));
    return a + b;
}

// ---------------------------------------------------------------------------
// Phase 1: merged_in GEMM; stores mt[b][l][t] = b_liq[l] + sum_d g*relu(.)
// (unchanged)
// ---------------------------------------------------------------------------
__global__ __launch_bounds__(256, 2)
void gemm_in_kernel(const float* __restrict__ x, const float* __restrict__ W_in,
                    const float* __restrict__ W_gate, const float* __restrict__ b_liq,
                    float* __restrict__ mt)
{
    __shared__ unsigned short As[128 * 32];
    __shared__ unsigned short Bs[128 * 32];

    const int tid = threadIdx.x;
    const int m0 = blockIdx.y * 128;
    const int n0 = blockIdx.x * 128;
    const int lane = tid & 63;
    const int wid  = tid >> 6;
    const int wr = wid >> 1, wc = wid & 1;
    const int fr = lane & 15, fq = lane >> 4;

    f32x4_t acc[4][4];
    #pragma unroll
    for (int i = 0; i < 4; ++i)
        #pragma unroll
        for (int j = 0; j < 4; ++j)
            acc[i][j] = (f32x4_t){0.f, 0.f, 0.f, 0.f};

    for (int k0 = 0; k0 < 512; k0 += 32) {
        #pragma unroll
        for (int p = 0; p < 4; ++p) {
            int ch = tid + p * 256;
            int r  = ch >> 3;
            int c  = ch & 7;
            float4 va = *(const float4*)(x    + (size_t)(m0 + r) * 512 + k0 + c * 4);
            float4 vb = *(const float4*)(W_in + (size_t)(n0 + r) * 512 + k0 + c * 4);
            ushort4 ha, hb;
            ha.x = f2bf(va.x); ha.y = f2bf(va.y); ha.z = f2bf(va.z); ha.w = f2bf(va.w);
            hb.x = f2bf(vb.x); hb.y = f2bf(vb.y); hb.z = f2bf(vb.z); hb.w = f2bf(vb.w);
            *(ushort4*)(&As[r * 32 + c * 4]) = ha;
            *(ushort4*)(&Bs[r * 32 + c * 4]) = hb;
        }
        __syncthreads();

        bf16x8 af[4], bfr[4];
        #pragma unroll
        for (int mi = 0; mi < 4; ++mi)
            af[mi] = *(const bf16x8*)(&As[(wr * 64 + mi * 16 + fr) * 32 + fq * 8]);
        #pragma unroll
        for (int ni = 0; ni < 4; ++ni)
            bfr[ni] = *(const bf16x8*)(&Bs[(wc * 64 + ni * 16 + fr) * 32 + fq * 8]);

        #pragma unroll
        for (int mi = 0; mi < 4; ++mi)
            #pragma unroll
            for (int ni = 0; ni < 4; ++ni)
                acc[mi][ni] = __builtin_amdgcn_mfma_f32_16x16x32_bf16(
                                  af[mi], bfr[ni], acc[mi][ni], 0, 0, 0);
        __syncthreads();
    }

    float gv[4], blq[4];
    #pragma unroll
    for (int ni = 0; ni < 4; ++ni) {
        int n = n0 + wc * 64 + ni * 16 + fr;
        gv[ni]  = 1.f / (1.f + __expf(-W_gate[n]));
        blq[ni] = b_liq[n >> 2];
    }
    #pragma unroll
    for (int mi = 0; mi < 4; ++mi) {
        #pragma unroll
        for (int ni = 0; ni < 4; ++ni) {
            int n = n0 + wc * 64 + ni * 16 + fr;
            int l = n >> 2;
            #pragma unroll
            for (int j = 0; j < 4; ++j) {
                float v = acc[mi][ni][j];
                float r = fmaxf(v, 0.f) * gv[ni];
                r += __shfl_xor(r, 1);
                r += __shfl_xor(r, 2);
                if ((lane & 3) == 0) {
                    int row = m0 + wr * 64 + mi * 16 + fq * 4 + j;   // m = b*512+t
                    int bb = row >> 9;
                    int tt = row & 511;
                    mt[(size_t)bb * 65536 + (size_t)l * 512 + tt] = r + blq[ni];
                }
            }
        }
    }
}

// ---------------------------------------------------------------------------
// Phase 2: recurrent scan — round-10 restructure: ONE barrier per step.
//  Phase A: MFMA from register-resident bfr -> li -> publish per-wave LN
//    partials (red2) + raw li values (li_buf, 1 ds_write_b32 per fr<8 lane,
//    conflict-free) -> single lds_barrier.
//  Phase B: every wave REDUNDANTLY computes the full state update: per lane
//    2 states (ds_read_b64 li_buf + 2 LN/tanh chains, bit-identical across
//    waves) -> cvt_pk to bf16 -> rebuild next bfr via 16 ds_bpermute
//    (register exchange, no second barrier, no LDS state buffer).
//  li_buf/red2 double-buffered by step parity (compile-time ph&1) to avoid
//  the cross-step write/read race.
// ---------------------------------------------------------------------------
__global__ __launch_bounds__(256, 1)
void scan_kernel(const float* __restrict__ mt, const float* __restrict__ W_liq,
                 const float* __restrict__ W_gate, const float* __restrict__ W_out,
                 const float* __restrict__ b_out, const float* __restrict__ ln_w,
                 const float* __restrict__ ln_b, const float* __restrict__ leaky,
                 float* __restrict__ out)
{
    __shared__ __align__(16) float li_buf[2][128];   // raw li, per step parity
    __shared__ __align__(16) float red2[2][8];       // per-wave {v1,v2} pairs
    __shared__ float s_final[128];

    const int tid  = threadIdx.x;
    const int b    = blockIdx.x;
    const int lane = tid & 63;
    const int w    = tid >> 6;        // wave 0..3
    const int fr   = lane & 15;
    const int fq   = lane >> 4;       // 0..3

    // W_liquid fragments, gate pre-folded, pinned in registers (bf16).
    bf16x8 wfrag[8][4];
    #pragma unroll
    for (int mi = 0; mi < 8; ++mi) {
        const int n = w * 128 + mi * 16 + fr;
        const float gn = 1.f / (1.f + __expf(-W_gate[n]));
        const float* wrow = W_liq + (size_t)n * 128;
        #pragma unroll
        for (int kk = 0; kk < 4; ++kk) {
            float4 f0 = *(const float4*)(wrow + kk * 32 + fq * 8);
            float4 f1 = *(const float4*)(wrow + kk * 32 + fq * 8 + 4);
            union { unsigned short u[8]; bf16x8 v; } cv;
            cv.u[0] = f2bf(gn * f0.x); cv.u[1] = f2bf(gn * f0.y);
            cv.u[2] = f2bf(gn * f0.z); cv.u[3] = f2bf(gn * f0.w);
            cv.u[4] = f2bf(gn * f1.x); cv.u[5] = f2bf(gn * f1.y);
            cv.u[6] = f2bf(gn * f1.z); cv.u[7] = f2bf(gn * f1.w);
            wfrag[mi][kk] = cv.v;
        }
    }

    size_t midx[8];
    #pragma unroll
    for (int mi = 0; mi < 8; ++mi)
        midx[mi] = (size_t)b * 65536 + (size_t)(w * 32 + mi * 4 + fq) * 512;

    // Phase-B ownership: lane updates states h0 = 2*lane, h1 = 2*lane+1
    // (redundantly in every wave -- bit-identical, deterministic).
    const int   h0  = 2 * lane;
    const float K2  = 2.8853900817779268f;             // 2*log2(e)
    const float lw20 = ln_w[h0] * K2,     lb20 = ln_b[h0] * K2;
    const float lw21 = ln_w[h0 + 1] * K2, lb21 = ln_b[h0 + 1] * K2;
    const float alpha = 1.f / (1.f + __expf(-leaky[0]));
    const float oma   = 1.f - alpha;
    const float n2a   = -2.f * alpha;

    float s0 = 0.f, s1 = 0.f;          // this lane's two states
    float c00 = alpha, c01 = alpha;    // c0 = oma*s + alpha, kept off-chain

    bf16x8 bfr[4];                     // state B-fragments, register-resident
    #pragma unroll
    for (int kk = 0; kk < 4; ++kk) bfr[kk] = (bf16x8)(__bf16)0.0f;

    float4 cur4[8], nxt4[8];
    #pragma unroll
    for (int mi = 0; mi < 8; ++mi) cur4[mi] = *(const float4*)(mt + midx[mi]);
    #pragma unroll
    for (int mi = 0; mi < 8; ++mi) nxt4[mi] = *(const float4*)(mt + midx[mi] + 4);

    const f32x4_t z = {0.f, 0.f, 0.f, 0.f};

    for (int ts = 0; ts < 512; ts += 4) {
        float4 ld4[8];
        if (ts < 504) {
            #pragma unroll
            for (int mi = 0; mi < 8; ++mi)
                ld4[mi] = *(const float4*)(mt + midx[mi] + ts + 8);
        }

        #pragma unroll
        for (int ph = 0; ph < 4; ++ph) {
            const int pb = ph & 1;     // compile-time buffer parity

            // ---- phase A: MFMA from register bfr ----
            f32x4_t a0[8], a1[8];
            #pragma unroll
            for (int mi = 0; mi < 8; ++mi) {
                a0[mi] = __builtin_amdgcn_mfma_f32_16x16x32_bf16(wfrag[mi][0], bfr[0], z, 0, 0, 0);
                a1[mi] = __builtin_amdgcn_mfma_f32_16x16x32_bf16(wfrag[mi][2], bfr[2], z, 0, 0, 0);
            }
            #pragma unroll
            for (int mi = 0; mi < 8; ++mi) {
                a0[mi] = __builtin_amdgcn_mfma_f32_16x16x32_bf16(wfrag[mi][1], bfr[1], a0[mi], 0, 0, 0);
                a1[mi] = __builtin_amdgcn_mfma_f32_16x16x32_bf16(wfrag[mi][3], bfr[3], a1[mi], 0, 0, 0);
            }

            float li[8];
            float v1a = 0.f, v1b = 0.f, v2a = 0.f, v2b = 0.f;
            #pragma unroll
            for (int mi = 0; mi < 8; ++mi) {
                f32x4_t s4 = a0[mi] + a1[mi];
                float mr = (fmaxf(s4[0], 0.f) + fmaxf(s4[1], 0.f))
                         + (fmaxf(s4[2], 0.f) + fmaxf(s4[3], 0.f));
                li[mi] = cur4[mi][ph] + mr;          // b_liq folded into mt
                if (mi & 1) { v1b += li[mi]; v2b = fmaf(li[mi], li[mi], v2b); }
                else        { v1a += li[mi]; v2a = fmaf(li[mi], li[mi], v2a); }
            }
            float v1 = v1a + v1b, v2 = v2a + v2b;

            // static-index select of li[fr&7] (cndmask tree; writers are fr<8)
            float sa = (fr & 1) ? li[1] : li[0];
            float sb = (fr & 1) ? li[3] : li[2];
            float sc = (fr & 1) ? li[5] : li[4];
            float sd = (fr & 1) ? li[7] : li[6];
            float se = (fr & 2) ? sb : sa;
            float sf = (fr & 2) ? sd : sc;
            float li_o = (fr & 4) ? sf : se;

            v1 = bfly16_add(v1);  v2 = bfly16_add(v2);
            v1 = bfly32_add(v1);  v2 = bfly32_add(v2);
            if (lane == 0) { red2[pb][2 * w] = v1; red2[pb][2 * w + 1] = v2; }
            // publish raw li: l = 32w + 4*(fr) + fq, conflict-free banks
            if (fr < 8) li_buf[pb][w * 32 + fr * 4 + fq] = li_o;
            lds_barrier();             // the ONLY barrier per step

            // ---- phase B: redundant full-state update ----
            float4 r0 = *(const float4*)&red2[pb][0], r1 = *(const float4*)&red2[pb][4];
            float S1 = (r0.x + r0.z) + (r1.x + r1.z);
            float S2 = (r0.y + r0.w) + (r1.y + r1.w);
            float mean = S1 * (1.f / 128.f);
            float var  = fmaf(-mean, mean, S2 * (1.f / 128.f));
            float rstd = __builtin_amdgcn_rsqf(var + 1e-5f);

            float2 liv = *(const float2*)&li_buf[pb][h0];   // ds_read_b64

            float q0  = rstd * lw20;
            float xn0 = fmaf(liv.x, q0, fmaf(-mean, q0, lb20));
            float e0  = __builtin_amdgcn_exp2f(xn0);
            float t0  = __builtin_amdgcn_rcpf(e0 + 1.f);
            s0  = fmaf(n2a, t0, c00);
            c00 = fmaf(oma, s0, alpha);

            float q1  = rstd * lw21;
            float xn1 = fmaf(liv.y, q1, fmaf(-mean, q1, lb21));
            float e1  = __builtin_amdgcn_exp2f(xn1);
            float t1  = __builtin_amdgcn_rcpf(e1 + 1.f);
            s1  = fmaf(n2a, t1, c01);
            c01 = fmaf(oma, s1, alpha);

            // pack the lane's 2 states: low 16 = state h0, high 16 = state h0+1
            unsigned sreg;
            asm("v_cvt_pk_bf16_f32 %0, %1, %2" : "=v"(sreg) : "v"(s0), "v"(s1));

            // rebuild bfr in-register: dword wd of bfr[kk] = states
            // {2L, 2L+1} with L = kk*16 + fq*4 + wd -> bpermute from lane L.
            #pragma unroll
            for (int kk = 0; kk < 4; ++kk) {
                union { int i[4]; bf16x8 v; } u;
                #pragma unroll
                for (int wd = 0; wd < 4; ++wd) {
                    int srcb = (kk * 16 + fq * 4 + wd) * 4;
                    u.i[wd] = __builtin_amdgcn_ds_bpermute(srcb, (int)sreg);
                }
                bfr[kk] = u.v;
            }
        }

        #pragma unroll
        for (int mi = 0; mi < 8; ++mi) cur4[mi] = nxt4[mi];
        if (ts < 504) {
            #pragma unroll
            for (int mi = 0; mi < 8; ++mi) nxt4[mi] = ld4[mi];
        }
    }

    // every wave holds the full final state; wave 0 publishes it
    if (w == 0) { s_final[h0] = s0; s_final[h0 + 1] = s1; }
    __syncthreads();
    if (tid < 2) {
        float accO = b_out[tid];
        #pragma unroll
        for (int h = 0; h < 128; ++h)
            accO = fmaf(s_final[h], W_out[tid * 128 + h], accO);
        out[b * 2 + tid] = accO;
    }
}

extern "C" void kernel_launch(void* const* d_in, const int* in_sizes, int n_in,
                              void* d_out, int out_size, void* d_ws, size_t ws_size,
                              hipStream_t stream)
{
    const float* x      = (const float*)d_in[0];
    const float* W_in   = (const float*)d_in[1];
    const float* W_liq  = (const float*)d_in[2];
    const float* W_gate = (const float*)d_in[3];
    const float* b_liq  = (const float*)d_in[4];
    const float* W_out  = (const float*)d_in[5];
    const float* b_out  = (const float*)d_in[6];
    const float* ln_w   = (const float*)d_in[7];
    const float* ln_b   = (const float*)d_in[8];
    const float* leaky  = (const float*)d_in[9];
    float* out = (float*)d_out;
    float* mt  = (float*)d_ws;    // transposed merged_in: [256][128][512] f32

    gemm_in_kernel<<<dim3(4, 1024), 256, 0, stream>>>(x, W_in, W_gate, b_liq, mt);
    scan_kernel<<<256, 256, 0, stream>>>(mt, W_liq, W_gate,
                                         W_out, b_out, ln_w, ln_b, leaky, out);
}

// Round 11
// 649.167 us; speedup vs baseline: 1.1047x; 1.1047x over previous
//
#include <hip/hip_runtime.h>
#include <hip/hip_bf16.h>
#include <stdint.h>

// Problem dims (fixed): B=256, T=512, I=512, L=128, D=4, O=2
// GEMM: M = B*T = 131072, N = L*D = 512, K = I = 512
// merged workspace layout: mt[b][l][t]  (t contiguous), b_liq folded in.

typedef __bf16 bf16x8 __attribute__((ext_vector_type(8)));
typedef float f32x4_t __attribute__((ext_vector_type(4)));

__device__ inline unsigned short f2bf(float f) {
    union { float f; unsigned u; } v; v.f = f;
    unsigned r = v.u + 0x7fffu + ((v.u >> 16) & 1u);   // round-to-nearest-even
    return (unsigned short)(r >> 16);
}

// 2x f32 -> packed bf16 dword in ONE instruction (RNE, same as f2bf).
__device__ inline unsigned cvt_pk_bf16(float lo, float hi) {
    unsigned r;
    asm("v_cvt_pk_bf16_f32 %0, %1, %2" : "=v"(r) : "v"(lo), "v"(hi));
    return r;
}

// LDS-only barrier: orders DS ops without draining vmcnt (keeps lane-private
// global prefetches in flight across it).
__device__ inline void lds_barrier() {
    asm volatile("s_waitcnt lgkmcnt(0)" ::: "memory");
    __builtin_amdgcn_s_barrier();
}

// VALU butterfly sums over lane-bit 4 / bit 5 (alias-proof, from R9).
__device__ inline float bfly16_add(float x) {
    float a, b;
    asm volatile("v_mov_b32 %0, %2\n\t"
                 "v_mov_b32 %1, %2\n\t"
                 "v_permlane16_swap_b32 %0, %1"
                 : "=&v"(a), "=&v"(b) : "v"(x));
    return a + b;
}
__device__ inline float bfly32_add(float x) {
    float a, b;
    asm volatile("v_mov_b32 %0, %2\n\t"
                 "v_mov_b32 %1, %2\n\t"
                 "v_permlane32_swap_b32 %0, %1"
                 : "=&v"(a), "=&v"(b) : "v"(x));
    return a + b;
}

// ---------------------------------------------------------------------------
// Phase 1: merged_in GEMM; stores mt[b][l][t] = b_liq[l] + sum_d g*relu(.)
// Round-11 change: staging f32->bf16 via v_cvt_pk_bf16_f32 (1 instr / 2 vals)
// instead of 5-op scalar f2bf — staging VALU per thread-iter 160 -> ~16.
// ---------------------------------------------------------------------------
__global__ __launch_bounds__(256, 2)
void gemm_in_kernel(const float* __restrict__ x, const float* __restrict__ W_in,
                    const float* __restrict__ W_gate, const float* __restrict__ b_liq,
                    float* __restrict__ mt)
{
    __shared__ unsigned short As[128 * 32];
    __shared__ unsigned short Bs[128 * 32];

    const int tid = threadIdx.x;
    const int m0 = blockIdx.y * 128;
    const int n0 = blockIdx.x * 128;
    const int lane = tid & 63;
    const int wid  = tid >> 6;
    const int wr = wid >> 1, wc = wid & 1;
    const int fr = lane & 15, fq = lane >> 4;

    f32x4_t acc[4][4];
    #pragma unroll
    for (int i = 0; i < 4; ++i)
        #pragma unroll
        for (int j = 0; j < 4; ++j)
            acc[i][j] = (f32x4_t){0.f, 0.f, 0.f, 0.f};

    for (int k0 = 0; k0 < 512; k0 += 32) {
        #pragma unroll
        for (int p = 0; p < 4; ++p) {
            int ch = tid + p * 256;
            int r  = ch >> 3;
            int c  = ch & 7;
            float4 va = *(const float4*)(x    + (size_t)(m0 + r) * 512 + k0 + c * 4);
            float4 vb = *(const float4*)(W_in + (size_t)(n0 + r) * 512 + k0 + c * 4);
            uint2 ua, ub;
            ua.x = cvt_pk_bf16(va.x, va.y);
            ua.y = cvt_pk_bf16(va.z, va.w);
            ub.x = cvt_pk_bf16(vb.x, vb.y);
            ub.y = cvt_pk_bf16(vb.z, vb.w);
            *(uint2*)(&As[r * 32 + c * 4]) = ua;    // 8B ds_write
            *(uint2*)(&Bs[r * 32 + c * 4]) = ub;
        }
        __syncthreads();

        bf16x8 af[4], bfr[4];
        #pragma unroll
        for (int mi = 0; mi < 4; ++mi)
            af[mi] = *(const bf16x8*)(&As[(wr * 64 + mi * 16 + fr) * 32 + fq * 8]);
        #pragma unroll
        for (int ni = 0; ni < 4; ++ni)
            bfr[ni] = *(const bf16x8*)(&Bs[(wc * 64 + ni * 16 + fr) * 32 + fq * 8]);

        #pragma unroll
        for (int mi = 0; mi < 4; ++mi)
            #pragma unroll
            for (int ni = 0; ni < 4; ++ni)
                acc[mi][ni] = __builtin_amdgcn_mfma_f32_16x16x32_bf16(
                                  af[mi], bfr[ni], acc[mi][ni], 0, 0, 0);
        __syncthreads();
    }

    float gv[4], blq[4];
    #pragma unroll
    for (int ni = 0; ni < 4; ++ni) {
        int n = n0 + wc * 64 + ni * 16 + fr;
        gv[ni]  = 1.f / (1.f + __expf(-W_gate[n]));
        blq[ni] = b_liq[n >> 2];
    }
    #pragma unroll
    for (int mi = 0; mi < 4; ++mi) {
        #pragma unroll
        for (int ni = 0; ni < 4; ++ni) {
            int n = n0 + wc * 64 + ni * 16 + fr;
            int l = n >> 2;
            #pragma unroll
            for (int j = 0; j < 4; ++j) {
                float v = acc[mi][ni][j];
                float r = fmaxf(v, 0.f) * gv[ni];
                r += __shfl_xor(r, 1);
                r += __shfl_xor(r, 2);
                if ((lane & 3) == 0) {
                    int row = m0 + wr * 64 + mi * 16 + fq * 4 + j;   // m = b*512+t
                    int bb = row >> 9;
                    int tt = row & 511;
                    mt[(size_t)bb * 65536 + (size_t)l * 512 + tt] = r + blq[ni];
                }
            }
        }
    }
}

// ---------------------------------------------------------------------------
// Phase 2: recurrent scan — R9 structure UNCHANGED (best known: 519 us).
// 4 waves, 1 batch/block, 2 barriers/step, permlane butterflies, partitioned
// phase B, exp2-folded LN, fused tanh+leaky.
// ---------------------------------------------------------------------------
__global__ __launch_bounds__(256, 1)
void scan_kernel(const float* __restrict__ mt, const float* __restrict__ W_liq,
                 const float* __restrict__ W_gate, const float* __restrict__ W_out,
                 const float* __restrict__ b_out, const float* __restrict__ ln_w,
                 const float* __restrict__ ln_b, const float* __restrict__ leaky,
                 float* __restrict__ out)
{
    __shared__ __align__(16) unsigned short s_bf[128];   // state, bf16
    __shared__ __align__(16) float red2[8];              // [w]={v1,v2} pairs
    __shared__ float s_final[128];

    const int tid  = threadIdx.x;
    const int b    = blockIdx.x;
    const int lane = tid & 63;
    const int w    = tid >> 6;        // wave 0..3
    const int fr   = lane & 15;
    const int fq   = lane >> 4;       // 0..3

    // W_liquid fragments, gate pre-folded, pinned in registers (bf16).
    bf16x8 wfrag[8][4];
    #pragma unroll
    for (int mi = 0; mi < 8; ++mi) {
        const int n = w * 128 + mi * 16 + fr;
        const float gn = 1.f / (1.f + __expf(-W_gate[n]));
        const float* wrow = W_liq + (size_t)n * 128;
        #pragma unroll
        for (int kk = 0; kk < 4; ++kk) {
            float4 f0 = *(const float4*)(wrow + kk * 32 + fq * 8);
            float4 f1 = *(const float4*)(wrow + kk * 32 + fq * 8 + 4);
            union { unsigned short u[8]; bf16x8 v; } cv;
            cv.u[0] = f2bf(gn * f0.x); cv.u[1] = f2bf(gn * f0.y);
            cv.u[2] = f2bf(gn * f0.z); cv.u[3] = f2bf(gn * f0.w);
            cv.u[4] = f2bf(gn * f1.x); cv.u[5] = f2bf(gn * f1.y);
            cv.u[6] = f2bf(gn * f1.z); cv.u[7] = f2bf(gn * f1.w);
            wfrag[mi][kk] = cv.v;
        }
    }

    size_t midx[8];
    #pragma unroll
    for (int mi = 0; mi < 8; ++mi)
        midx[mi] = (size_t)b * 65536 + (size_t)(w * 32 + mi * 4 + fq) * 512;

    // Phase-B ownership: lane finalizes l_own = 32w + 4*(fr&7) + fq.
    const int l_own  = w * 32 + (fr & 7) * 4 + fq;
    const float K2   = 2.8853900817779268f;              // 2*log2(e)
    const float lw2  = ln_w[l_own] * K2;
    const float lb2  = ln_b[l_own] * K2;
    const float alpha = 1.f / (1.f + __expf(-leaky[0]));
    const float oma   = 1.f - alpha;
    const float n2a   = -2.f * alpha;

    float s_own = 0.f;
    float c0    = alpha;               // c0 = oma*s_own + alpha (s_own = 0)

    float4 cur4[8], nxt4[8];
    #pragma unroll
    for (int mi = 0; mi < 8; ++mi) cur4[mi] = *(const float4*)(mt + midx[mi]);
    #pragma unroll
    for (int mi = 0; mi < 8; ++mi) nxt4[mi] = *(const float4*)(mt + midx[mi] + 4);

    if (tid < 64) ((unsigned*)s_bf)[tid] = 0u;   // state_0 = 0
    lds_barrier();

    const f32x4_t z = {0.f, 0.f, 0.f, 0.f};

    for (int ts = 0; ts < 512; ts += 4) {
        float4 ld4[8];
        if (ts < 504) {
            #pragma unroll
            for (int mi = 0; mi < 8; ++mi)
                ld4[mi] = *(const float4*)(mt + midx[mi] + ts + 8);
        }

        #pragma unroll
        for (int ph = 0; ph < 4; ++ph) {
            // ---- phase A ----
            bf16x8 bfr[4];
            #pragma unroll
            for (int kk = 0; kk < 4; ++kk)
                bfr[kk] = *(const bf16x8*)(&s_bf[kk * 32 + fq * 8]);

            f32x4_t a0[8], a1[8];
            #pragma unroll
            for (int mi = 0; mi < 8; ++mi) {
                a0[mi] = __builtin_amdgcn_mfma_f32_16x16x32_bf16(wfrag[mi][0], bfr[0], z, 0, 0, 0);
                a1[mi] = __builtin_amdgcn_mfma_f32_16x16x32_bf16(wfrag[mi][2], bfr[2], z, 0, 0, 0);
            }
            #pragma unroll
            for (int mi = 0; mi < 8; ++mi) {
                a0[mi] = __builtin_amdgcn_mfma_f32_16x16x32_bf16(wfrag[mi][1], bfr[1], a0[mi], 0, 0, 0);
                a1[mi] = __builtin_amdgcn_mfma_f32_16x16x32_bf16(wfrag[mi][3], bfr[3], a1[mi], 0, 0, 0);
            }

            float li[8];
            float v1a = 0.f, v1b = 0.f, v2a = 0.f, v2b = 0.f;
            #pragma unroll
            for (int mi = 0; mi < 8; ++mi) {
                f32x4_t s4 = a0[mi] + a1[mi];
                float mr = (fmaxf(s4[0], 0.f) + fmaxf(s4[1], 0.f))
                         + (fmaxf(s4[2], 0.f) + fmaxf(s4[3], 0.f));
                li[mi] = cur4[mi][ph] + mr;          // b_liq folded into mt
                if (mi & 1) { v1b += li[mi]; v2b = fmaf(li[mi], li[mi], v2b); }
                else        { v1a += li[mi]; v2a = fmaf(li[mi], li[mi], v2a); }
            }
            float v1 = v1a + v1b, v2 = v2a + v2b;

            // select li[fr&7] (pre-barrier; runs parallel to the reduction)
            float sa = (fr & 1) ? li[1] : li[0];
            float sb = (fr & 1) ? li[3] : li[2];
            float sc = (fr & 1) ? li[5] : li[4];
            float sd = (fr & 1) ? li[7] : li[6];
            float se = (fr & 2) ? sb : sa;
            float sf = (fr & 2) ? sd : sc;
            float li_o = (fr & 4) ? sf : se;

            // VALU butterflies over lane bits 4,5 (fq groups); fr preserved
            v1 = bfly16_add(v1);  v2 = bfly16_add(v2);
            v1 = bfly32_add(v1);  v2 = bfly32_add(v2);
            if (lane == 0) { red2[2 * w] = v1; red2[2 * w + 1] = v2; }
            lds_barrier();

            // ---- phase B ----
            float4 r0 = *(const float4*)&red2[0], r1 = *(const float4*)&red2[4];
            float S1 = (r0.x + r0.z) + (r1.x + r1.z);
            float S2 = (r0.y + r0.w) + (r1.y + r1.w);
            float mean = S1 * (1.f / 128.f);
            float var  = fmaf(-mean, mean, S2 * (1.f / 128.f));
            float rstd = __builtin_amdgcn_rsqf(var + 1e-5f);

            float q  = rstd * lw2;
            float xn = fmaf(li_o, q, fmaf(-mean, q, lb2));   // 2*log2e*(LN out)
            float e  = __builtin_amdgcn_exp2f(xn);           // e^{2*lnout}
            float r  = __builtin_amdgcn_rcpf(e + 1.f);
            s_own    = fmaf(n2a, r, c0);                     // (1-a)s + a*tanh
            c0       = fmaf(oma, s_own, alpha);              // for next step

            unsigned cvt;
            asm("v_cvt_pk_bf16_f32 %0, %1, %2" : "=v"(cvt) : "v"(s_own), "v"(0.f));
            if (fr < 8) s_bf[l_own] = (unsigned short)cvt;
            lds_barrier();
        }

        #pragma unroll
        for (int mi = 0; mi < 8; ++mi) cur4[mi] = nxt4[mi];
        if (ts < 504) {
            #pragma unroll
            for (int mi = 0; mi < 8; ++mi) nxt4[mi] = ld4[mi];
        }
    }

    if (fr < 8) s_final[l_own] = s_own;
    __syncthreads();
    if (tid < 2) {
        float accO = b_out[tid];
        #pragma unroll
        for (int h = 0; h < 128; ++h)
            accO = fmaf(s_final[h], W_out[tid * 128 + h], accO);
        out[b * 2 + tid] = accO;
    }
}

extern "C" void kernel_launch(void* const* d_in, const int* in_sizes, int n_in,
                              void* d_out, int out_size, void* d_ws, size_t ws_size,
                              hipStream_t stream)
{
    const float* x      = (const float*)d_in[0];
    const float* W_in   = (const float*)d_in[1];
    const float* W_liq  = (const float*)d_in[2];
    const float* W_gate = (const float*)d_in[3];
    const float* b_liq  = (const float*)d_in[4];
    const float* W_out  = (const float*)d_in[5];
    const float* b_out  = (const float*)d_in[6];
    const float* ln_w   = (const float*)d_in[7];
    const float* ln_b   = (const float*)d_in[8];
    const float* leaky  = (const float*)d_in[9];
    float* out = (float*)d_out;
    float* mt  = (float*)d_ws;    // transposed merged_in: [256][128][512] f32

    gemm_in_kernel<<<dim3(4, 1024), 256, 0, stream>>>(x, W_in, W_gate, b_liq, mt);
    scan_kernel<<<256, 256, 0, stream>>>(mt, W_liq, W_gate,
                                         W_out, b_out, ln_w, ln_b, leaky, out);
}

// Round 12
// 629.509 us; speedup vs baseline: 1.1392x; 1.0312x over previous
//
#include <hip/hip_runtime.h>
#include <hip/hip_bf16.h>
#include <stdint.h>

// Problem dims (fixed): B=256, T=512, I=512, L=128, D=4, O=2
// GEMM: M = B*T = 131072, N = L*D = 512, K = I = 512
// merged workspace layout: mt[b][l][t]  (t contiguous), b_liq folded in.

typedef __bf16 bf16x8 __attribute__((ext_vector_type(8)));
typedef float f32x4_t __attribute__((ext_vector_type(4)));

__device__ inline unsigned short f2bf(float f) {
    union { float f; unsigned u; } v; v.f = f;
    unsigned r = v.u + 0x7fffu + ((v.u >> 16) & 1u);   // round-to-nearest-even
    return (unsigned short)(r >> 16);
}

// 2x f32 -> packed bf16 dword in ONE instruction (RNE, same as f2bf).
__device__ inline unsigned cvt_pk_bf16(float lo, float hi) {
    unsigned r;
    asm("v_cvt_pk_bf16_f32 %0, %1, %2" : "=v"(r) : "v"(lo), "v"(hi));
    return r;
}

// LDS-only barrier: orders DS ops without draining vmcnt (keeps lane-private
// global prefetches in flight across it).
__device__ inline void lds_barrier() {
    asm volatile("s_waitcnt lgkmcnt(0)" ::: "memory");
    __builtin_amdgcn_s_barrier();
}

// VALU butterfly sums over lane-bit 4 / bit 5 (alias-proof, from R9).
__device__ inline float bfly16_add(float x) {
    float a, b;
    asm volatile("v_mov_b32 %0, %2\n\t"
                 "v_mov_b32 %1, %2\n\t"
                 "v_permlane16_swap_b32 %0, %1"
                 : "=&v"(a), "=&v"(b) : "v"(x));
    return a + b;
}
__device__ inline float bfly32_add(float x) {
    float a, b;
    asm volatile("v_mov_b32 %0, %2\n\t"
                 "v_mov_b32 %1, %2\n\t"
                 "v_permlane32_swap_b32 %0, %1"
                 : "=&v"(a), "=&v"(b) : "v"(x));
    return a + b;
}

// ---------------------------------------------------------------------------
// Phase 1: merged_in GEMM; stores mt[b][l][t] = b_liq[l] + sum_d g*relu(.)
// Round-12: XCD-aware work remap. Dispatch id -> XCD is round-robin (id%8),
// so assign the 4 n-blocks of one m-tile to the SAME XCD at nearby dispatch
// slots: the shared 256KB x-tile is fetched into that XCD's L2 once and hit
// 3 more times (was: 4 XCDs -> 4x HBM traffic on x, which exceeds L3).
// ---------------------------------------------------------------------------
__global__ __launch_bounds__(256, 2)
void gemm_in_kernel(const float* __restrict__ x, const float* __restrict__ W_in,
                    const float* __restrict__ W_gate, const float* __restrict__ b_liq,
                    float* __restrict__ mt)
{
    __shared__ unsigned short As[128 * 32];
    __shared__ unsigned short Bs[128 * 32];

    const int tid = threadIdx.x;
    const int wid  = blockIdx.x;          // 0..4095
    const int xcd  = wid & 7;             // this block's XCD (dispatch % 8)
    const int slot = wid >> 3;            // 0..511 within the XCD
    const int n0 = (slot & 3) * 128;      // 4 n-blocks consecutive per XCD
    const int m0 = ((slot >> 2) + xcd * 128) * 128;   // 128 m-tiles per XCD

    const int lane = tid & 63;
    const int widw = tid >> 6;
    const int wr = widw >> 1, wc = widw & 1;
    const int fr = lane & 15, fq = lane >> 4;

    f32x4_t acc[4][4];
    #pragma unroll
    for (int i = 0; i < 4; ++i)
        #pragma unroll
        for (int j = 0; j < 4; ++j)
            acc[i][j] = (f32x4_t){0.f, 0.f, 0.f, 0.f};

    for (int k0 = 0; k0 < 512; k0 += 32) {
        #pragma unroll
        for (int p = 0; p < 4; ++p) {
            int ch = tid + p * 256;
            int r  = ch >> 3;
            int c  = ch & 7;
            float4 va = *(const float4*)(x    + (size_t)(m0 + r) * 512 + k0 + c * 4);
            float4 vb = *(const float4*)(W_in + (size_t)(n0 + r) * 512 + k0 + c * 4);
            uint2 ua, ub;
            ua.x = cvt_pk_bf16(va.x, va.y);
            ua.y = cvt_pk_bf16(va.z, va.w);
            ub.x = cvt_pk_bf16(vb.x, vb.y);
            ub.y = cvt_pk_bf16(vb.z, vb.w);
            *(uint2*)(&As[r * 32 + c * 4]) = ua;    // 8B ds_write
            *(uint2*)(&Bs[r * 32 + c * 4]) = ub;
        }
        __syncthreads();

        bf16x8 af[4], bfr[4];
        #pragma unroll
        for (int mi = 0; mi < 4; ++mi)
            af[mi] = *(const bf16x8*)(&As[(wr * 64 + mi * 16 + fr) * 32 + fq * 8]);
        #pragma unroll
        for (int ni = 0; ni < 4; ++ni)
            bfr[ni] = *(const bf16x8*)(&Bs[(wc * 64 + ni * 16 + fr) * 32 + fq * 8]);

        #pragma unroll
        for (int mi = 0; mi < 4; ++mi)
            #pragma unroll
            for (int ni = 0; ni < 4; ++ni)
                acc[mi][ni] = __builtin_amdgcn_mfma_f32_16x16x32_bf16(
                                  af[mi], bfr[ni], acc[mi][ni], 0, 0, 0);
        __syncthreads();
    }

    float gv[4], blq[4];
    #pragma unroll
    for (int ni = 0; ni < 4; ++ni) {
        int n = n0 + wc * 64 + ni * 16 + fr;
        gv[ni]  = 1.f / (1.f + __expf(-W_gate[n]));
        blq[ni] = b_liq[n >> 2];
    }
    #pragma unroll
    for (int mi = 0; mi < 4; ++mi) {
        #pragma unroll
        for (int ni = 0; ni < 4; ++ni) {
            int n = n0 + wc * 64 + ni * 16 + fr;
            int l = n >> 2;
            #pragma unroll
            for (int j = 0; j < 4; ++j) {
                float v = acc[mi][ni][j];
                float r = fmaxf(v, 0.f) * gv[ni];
                r += __shfl_xor(r, 1);
                r += __shfl_xor(r, 2);
                if ((lane & 3) == 0) {
                    int row = m0 + wr * 64 + mi * 16 + fq * 4 + j;   // m = b*512+t
                    int bb = row >> 9;
                    int tt = row & 511;
                    mt[(size_t)bb * 65536 + (size_t)l * 512 + tt] = r + blq[ni];
                }
            }
        }
    }
}

// ---------------------------------------------------------------------------
// Phase 2: recurrent scan — R9 structure UNCHANGED (best known: 519 us).
// 4 waves, 1 batch/block, 2 barriers/step, permlane butterflies, partitioned
// phase B, exp2-folded LN, fused tanh+leaky.
// ---------------------------------------------------------------------------
__global__ __launch_bounds__(256, 1)
void scan_kernel(const float* __restrict__ mt, const float* __restrict__ W_liq,
                 const float* __restrict__ W_gate, const float* __restrict__ W_out,
                 const float* __restrict__ b_out, const float* __restrict__ ln_w,
                 const float* __restrict__ ln_b, const float* __restrict__ leaky,
                 float* __restrict__ out)
{
    __shared__ __align__(16) unsigned short s_bf[128];   // state, bf16
    __shared__ __align__(16) float red2[8];              // [w]={v1,v2} pairs
    __shared__ float s_final[128];

    const int tid  = threadIdx.x;
    const int b    = blockIdx.x;
    const int lane = tid & 63;
    const int w    = tid >> 6;        // wave 0..3
    const int fr   = lane & 15;
    const int fq   = lane >> 4;       // 0..3

    // W_liquid fragments, gate pre-folded, pinned in registers (bf16).
    bf16x8 wfrag[8][4];
    #pragma unroll
    for (int mi = 0; mi < 8; ++mi) {
        const int n = w * 128 + mi * 16 + fr;
        const float gn = 1.f / (1.f + __expf(-W_gate[n]));
        const float* wrow = W_liq + (size_t)n * 128;
        #pragma unroll
        for (int kk = 0; kk < 4; ++kk) {
            float4 f0 = *(const float4*)(wrow + kk * 32 + fq * 8);
            float4 f1 = *(const float4*)(wrow + kk * 32 + fq * 8 + 4);
            union { unsigned short u[8]; bf16x8 v; } cv;
            cv.u[0] = f2bf(gn * f0.x); cv.u[1] = f2bf(gn * f0.y);
            cv.u[2] = f2bf(gn * f0.z); cv.u[3] = f2bf(gn * f0.w);
            cv.u[4] = f2bf(gn * f1.x); cv.u[5] = f2bf(gn * f1.y);
            cv.u[6] = f2bf(gn * f1.z); cv.u[7] = f2bf(gn * f1.w);
            wfrag[mi][kk] = cv.v;
        }
    }

    size_t midx[8];
    #pragma unroll
    for (int mi = 0; mi < 8; ++mi)
        midx[mi] = (size_t)b * 65536 + (size_t)(w * 32 + mi * 4 + fq) * 512;

    // Phase-B ownership: lane finalizes l_own = 32w + 4*(fr&7) + fq.
    const int l_own  = w * 32 + (fr & 7) * 4 + fq;
    const float K2   = 2.8853900817779268f;              // 2*log2(e)
    const float lw2  = ln_w[l_own] * K2;
    const float lb2  = ln_b[l_own] * K2;
    const float alpha = 1.f / (1.f + __expf(-leaky[0]));
    const float oma   = 1.f - alpha;
    const float n2a   = -2.f * alpha;

    float s_own = 0.f;
    float c0    = alpha;               // c0 = oma*s_own + alpha (s_own = 0)

    float4 cur4[8], nxt4[8];
    #pragma unroll
    for (int mi = 0; mi < 8; ++mi) cur4[mi] = *(const float4*)(mt + midx[mi]);
    #pragma unroll
    for (int mi = 0; mi < 8; ++mi) nxt4[mi] = *(const float4*)(mt + midx[mi] + 4);

    if (tid < 64) ((unsigned*)s_bf)[tid] = 0u;   // state_0 = 0
    lds_barrier();

    const f32x4_t z = {0.f, 0.f, 0.f, 0.f};

    for (int ts = 0; ts < 512; ts += 4) {
        float4 ld4[8];
        if (ts < 504) {
            #pragma unroll
            for (int mi = 0; mi < 8; ++mi)
                ld4[mi] = *(const float4*)(mt + midx[mi] + ts + 8);
        }

        #pragma unroll
        for (int ph = 0; ph < 4; ++ph) {
            // ---- phase A ----
            bf16x8 bfr[4];
            #pragma unroll
            for (int kk = 0; kk < 4; ++kk)
                bfr[kk] = *(const bf16x8*)(&s_bf[kk * 32 + fq * 8]);

            f32x4_t a0[8], a1[8];
            #pragma unroll
            for (int mi = 0; mi < 8; ++mi) {
                a0[mi] = __builtin_amdgcn_mfma_f32_16x16x32_bf16(wfrag[mi][0], bfr[0], z, 0, 0, 0);
                a1[mi] = __builtin_amdgcn_mfma_f32_16x16x32_bf16(wfrag[mi][2], bfr[2], z, 0, 0, 0);
            }
            #pragma unroll
            for (int mi = 0; mi < 8; ++mi) {
                a0[mi] = __builtin_amdgcn_mfma_f32_16x16x32_bf16(wfrag[mi][1], bfr[1], a0[mi], 0, 0, 0);
                a1[mi] = __builtin_amdgcn_mfma_f32_16x16x32_bf16(wfrag[mi][3], bfr[3], a1[mi], 0, 0, 0);
            }

            float li[8];
            float v1a = 0.f, v1b = 0.f, v2a = 0.f, v2b = 0.f;
            #pragma unroll
            for (int mi = 0; mi < 8; ++mi) {
                f32x4_t s4 = a0[mi] + a1[mi];
                float mr = (fmaxf(s4[0], 0.f) + fmaxf(s4[1], 0.f))
                         + (fmaxf(s4[2], 0.f) + fmaxf(s4[3], 0.f));
                li[mi] = cur4[mi][ph] + mr;          // b_liq folded into mt
                if (mi & 1) { v1b += li[mi]; v2b = fmaf(li[mi], li[mi], v2b); }
                else        { v1a += li[mi]; v2a = fmaf(li[mi], li[mi], v2a); }
            }
            float v1 = v1a + v1b, v2 = v2a + v2b;

            // select li[fr&7] (pre-barrier; runs parallel to the reduction)
            float sa = (fr & 1) ? li[1] : li[0];
            float sb = (fr & 1) ? li[3] : li[2];
            float sc = (fr & 1) ? li[5] : li[4];
            float sd = (fr & 1) ? li[7] : li[6];
            float se = (fr & 2) ? sb : sa;
            float sf = (fr & 2) ? sd : sc;
            float li_o = (fr & 4) ? sf : se;

            // VALU butterflies over lane bits 4,5 (fq groups); fr preserved
            v1 = bfly16_add(v1);  v2 = bfly16_add(v2);
            v1 = bfly32_add(v1);  v2 = bfly32_add(v2);
            if (lane == 0) { red2[2 * w] = v1; red2[2 * w + 1] = v2; }
            lds_barrier();

            // ---- phase B ----
            float4 r0 = *(const float4*)&red2[0], r1 = *(const float4*)&red2[4];
            float S1 = (r0.x + r0.z) + (r1.x + r1.z);
            float S2 = (r0.y + r0.w) + (r1.y + r1.w);
            float mean = S1 * (1.f / 128.f);
            float var  = fmaf(-mean, mean, S2 * (1.f / 128.f));
            float rstd = __builtin_amdgcn_rsqf(var + 1e-5f);

            float q  = rstd * lw2;
            float xn = fmaf(li_o, q, fmaf(-mean, q, lb2));   // 2*log2e*(LN out)
            float e  = __builtin_amdgcn_exp2f(xn);           // e^{2*lnout}
            float r  = __builtin_amdgcn_rcpf(e + 1.f);
            s_own    = fmaf(n2a, r, c0);                     // (1-a)s + a*tanh
            c0       = fmaf(oma, s_own, alpha);              // for next step

            unsigned cvt;
            asm("v_cvt_pk_bf16_f32 %0, %1, %2" : "=v"(cvt) : "v"(s_own), "v"(0.f));
            if (fr < 8) s_bf[l_own] = (unsigned short)cvt;
            lds_barrier();
        }

        #pragma unroll
        for (int mi = 0; mi < 8; ++mi) cur4[mi] = nxt4[mi];
        if (ts < 504) {
            #pragma unroll
            for (int mi = 0; mi < 8; ++mi) nxt4[mi] = ld4[mi];
        }
    }

    if (fr < 8) s_final[l_own] = s_own;
    __syncthreads();
    if (tid < 2) {
        float accO = b_out[tid];
        #pragma unroll
        for (int h = 0; h < 128; ++h)
            accO = fmaf(s_final[h], W_out[tid * 128 + h], accO);
        out[b * 2 + tid] = accO;
    }
}

extern "C" void kernel_launch(void* const* d_in, const int* in_sizes, int n_in,
                              void* d_out, int out_size, void* d_ws, size_t ws_size,
                              hipStream_t stream)
{
    const float* x      = (const float*)d_in[0];
    const float* W_in   = (const float*)d_in[1];
    const float* W_liq  = (const float*)d_in[2];
    const float* W_gate = (const float*)d_in[3];
    const float* b_liq  = (const float*)d_in[4];
    const float* W_out  = (const float*)d_in[5];
    const float* b_out  = (const float*)d_in[6];
    const float* ln_w   = (const float*)d_in[7];
    const float* ln_b   = (const float*)d_in[8];
    const float* leaky  = (const float*)d_in[9];
    float* out = (float*)d_out;
    float* mt  = (float*)d_ws;    // transposed merged_in: [256][128][512] f32

    gemm_in_kernel<<<4096, 256, 0, stream>>>(x, W_in, W_gate, b_liq, mt);
    scan_kernel<<<256, 256, 0, stream>>>(mt, W_liq, W_gate,
                                         W_out, b_out, ln_w, ln_b, leaky, out);
}